// Round 8
// baseline (415.599 us; speedup 1.0000x reference)
//
#include <hip/hip_runtime.h>
#include <math.h>

#define NN 50000
#define EE 800000
#define IN_F 30
#define NH 8
#define DH 32
#define HD 256      // NH*DH
#define NG 512
#define NHID 128
#define ALPHA 0.2f
#define CAP 64      // fixed bucket capacity; P(Poisson(16)>64) ~ 1e-19, guarded

#define P1B (NN/16)                           // proj1 blocks (3125)
#define SCB ((EE+255)/256)                    // scatter blocks (3125)
#define GB  ((NN+255)/256)                    // boundary blocks (196)

typedef unsigned short u16;
typedef __attribute__((ext_vector_type(8))) short bf16x8;
typedef __attribute__((ext_vector_type(4))) float f32x4;
typedef __attribute__((ext_vector_type(2))) float f32x2;

// ---------- bf16 helpers (round-to-nearest-even) ----------
__device__ __forceinline__ u16 f2bf(float f){
  unsigned u = __float_as_uint(f);
  u = u + 0x7FFFu + ((u >> 16) & 1u);
  return (u16)(u >> 16);
}
__device__ __forceinline__ float bf2f(u16 b){
  return __uint_as_float(((unsigned)b) << 16);
}
__device__ __forceinline__ float4 bf4_to_f4(ushort4 v){
  float4 r; r.x=bf2f(v.x); r.y=bf2f(v.y); r.z=bf2f(v.z); r.w=bf2f(v.w); return r;
}

// ---------- bucket scatter (low-VGPR standalone) + gstart from sorted gid ----
// blocks [0,SCB): p = atomicAdd(cnt[dst]); buck[dst*CAP+p] = (u16)src
// blocks [SCB,SCB+GB): graph segment starts via boundary detection (no atomics)
__global__ void k_scatter(const int* __restrict__ dst, const int* __restrict__ src,
                          const int* __restrict__ gid,
                          int* cnt, u16* __restrict__ buck, int* __restrict__ gstart){
  int bid = blockIdx.x;
  if(bid < SCB){
    int i = bid*256 + threadIdx.x;
    if(i<EE){
      int d = dst[i];
      int p = atomicAdd(&cnt[d],1);
      if(p<CAP) buck[d*CAP+p] = (u16)src[i];
    }
    return;
  }
  int i = (bid-SCB)*256 + threadIdx.x;
  if(i<NN){
    int g  = gid[i];
    int gp = (i>0)? gid[i-1] : -1;
    for(int gg=gp+1; gg<=g; gg++) gstart[gg]=i;   // total writes over grid = NG
    if(i==NN-1){
      for(int gg=g+1; gg<=NG; gg++) gstart[gg]=NN;
    }
  }
}

// ---------- layer-1 projection + FUSED el1/er1 epilogue + W2 transpose tail ----
#define TM1 16
__global__ void k_proj1w(const float* __restrict__ x, const float* __restrict__ W1,
                         u16* __restrict__ feat16, const float* __restrict__ W2,
                         u16* __restrict__ W2T,
                         const float* __restrict__ al, const float* __restrict__ ar,
                         u16* __restrict__ elb, float* __restrict__ er){
  if(blockIdx.x >= P1B){                       // W2T tail: 256 blocks
    int i = (blockIdx.x - P1B)*256 + threadIdx.x;   // < HD*HD
    int n = i >> 8, k = i & 255;
    W2T[i] = f2bf(W2[k*HD + n]);
    return;                                    // block-uniform exit (no barrier crossed)
  }
  __shared__ float xs[TM1][IN_F];
  int n0 = blockIdx.x*TM1;
  int t = threadIdx.x;
  for(int i=t;i<TM1*IN_F;i+=256){
    int m=i/IN_F, k=i-m*IN_F;
    xs[m][k] = x[(size_t)(n0+m)*IN_F+k];
  }
  __syncthreads();
  int L = t & 63;
  int jq = L << 2;
  int m0 = t >> 6;
  float4 acc[4];
  #pragma unroll
  for(int r=0;r<4;r++){ acc[r].x=0.f; acc[r].y=0.f; acc[r].z=0.f; acc[r].w=0.f; }
  for(int k=0;k<IN_F;k++){
    float4 w = *(const float4*)&W1[k*HD + jq];
    #pragma unroll
    for(int r=0;r<4;r++){
      float xv = xs[m0 + (r<<2)][k];
      acc[r].x += xv*w.x; acc[r].y += xv*w.y; acc[r].z += xv*w.z; acc[r].w += xv*w.w;
    }
  }
  #pragma unroll
  for(int r=0;r<4;r++){
    int n = n0 + m0 + (r<<2);
    ushort4 o; o.x=f2bf(acc[r].x); o.y=f2bf(acc[r].y); o.z=f2bf(acc[r].z); o.w=f2bf(acc[r].w);
    *(ushort4*)&feat16[(size_t)n*HD + jq] = o;
  }
  // ---- fused el/er from f32 accumulators (el stored bf16) ----
  int h = L >> 3;
  float4 av = *(const float4*)&al[jq];
  float4 rv = *(const float4*)&ar[jq];
  #pragma unroll
  for(int r=0;r<4;r++){
    float pe = acc[r].x*av.x + acc[r].y*av.y + acc[r].z*av.z + acc[r].w*av.w;
    float pr = acc[r].x*rv.x + acc[r].y*rv.y + acc[r].z*rv.z + acc[r].w*rv.w;
    #pragma unroll
    for(int off=1; off<8; off<<=1){
      pe += __shfl_xor(pe, off, 64);
      pr += __shfl_xor(pr, off, 64);
    }
    if((L & 7) == 0){
      int n = n0 + m0 + (r<<2);
      elb[(size_t)n*NH + h] = f2bf(pe);
      er[(size_t)n*NH + h]  = pr;
    }
  }
}

// ---------- layer-2 projection via MFMA + el2/er2 epilogue ----------
__global__ void k_proj2m(const u16* __restrict__ h1b, const u16* __restrict__ W2T,
                         u16* __restrict__ Y16,
                         const float* __restrict__ al, const float* __restrict__ ar,
                         u16* __restrict__ elb, float* __restrict__ er){
  int t = threadIdx.x;
  int wave = t>>6, lane = t&63;
  int m0 = blockIdx.x*64 + wave*16;
  int lm = lane & 15, lq = lane >> 4;
  int arow = m0 + lm; if(arow >= NN) arow = NN-1;   // clamp (stores guarded)
  const u16* Aptr = h1b + (size_t)arow*HD + lq*8;
  f32x4 acc[16];
  #pragma unroll
  for(int ct=0;ct<16;ct++) acc[ct] = (f32x4){0.f,0.f,0.f,0.f};
  #pragma unroll
  for(int k0=0;k0<HD;k0+=32){
    bf16x8 a = *(const bf16x8*)(Aptr + k0);
    #pragma unroll
    for(int ct=0;ct<16;ct++){
      bf16x8 b = *(const bf16x8*)(W2T + (size_t)(ct*16 + lm)*HD + k0 + lq*8);
      acc[ct] = __builtin_amdgcn_mfma_f32_16x16x32_bf16(a, b, acc[ct], 0, 0, 0);
    }
  }
  int orow0 = m0 + lq*4;
  #pragma unroll
  for(int ct=0;ct<16;ct++){
    #pragma unroll
    for(int r=0;r<4;r++){
      int n = orow0 + r;
      if(n < NN) Y16[(size_t)n*HD + ct*16 + lm] = f2bf(acc[ct][r]);
    }
  }
  // ---- fused el/er from f32 accumulators ----
  #pragma unroll
  for(int h=0;h<NH;h++){
    float av0 = al[h*DH + lm],      rv0 = ar[h*DH + lm];
    float av1 = al[h*DH + 16 + lm], rv1 = ar[h*DH + 16 + lm];
    #pragma unroll
    for(int r=0;r<4;r++){
      float pe = acc[2*h][r]*av0 + acc[2*h+1][r]*av1;
      float pr = acc[2*h][r]*rv0 + acc[2*h+1][r]*rv1;
      #pragma unroll
      for(int off=1; off<16; off<<=1){
        pe += __shfl_xor(pe, off, 64);
        pr += __shfl_xor(pr, off, 64);
      }
      if(lm == 0){
        int n = orow0 + r;
        if(n < NN){
          elb[(size_t)n*NH + h] = f2bf(pe);
          er[(size_t)n*NH + h]  = pr;
        }
      }
    }
  }
}

// ---------- per-node softmax aggregation, single 64-edge bucket chunk ----------
// Phase A: lane computes 8-head weights for its own edge -> LDS (16B).
// Phase B: aggregation reads w from LDS. Wave-synchronous (no __syncthreads).
__device__ __forceinline__ void gat_aggw(int n, int lane, u16* wlds,
    const u16* __restrict__ feat16,
    const u16* __restrict__ elb, const float* __restrict__ er,
    const int* __restrict__ cnt_arr, const u16* __restrict__ buck, float* A){
  int half = lane >> 5;
  int l = lane & 31;
  int h = l >> 2;
  int col8 = l << 3;
  int cnt = cnt_arr[n];
  int lim = cnt < CAP ? cnt : CAP;
  int base = n*CAP;
  float4 e0 = *(const float4*)&er[(size_t)n*NH];
  float4 e1 = *(const float4*)&er[(size_t)n*NH + 4];
  float s = 0.f;
  f32x2 A2[4];
  #pragma unroll
  for(int j=0;j<4;j++) A2[j]=(f32x2){0.f,0.f};
  int myIdx = (int)buck[base + (lane < lim ? lane : (lim>0? lim-1 : 0))];
  // ---- phase A: weights for edge (base+lane), all 8 heads -> LDS ----
  if(lane < lim){
    uint4 eb = *(const uint4*)&elb[(size_t)myIdx*NH];   // 8 bf16
    float v; ushort4 q0, q1;
    v = bf2f((u16)(eb.x & 0xffff)) + e0.x; v = fmaxf(v, ALPHA*v); q0.x = f2bf(__expf(v));
    v = bf2f((u16)(eb.x >> 16))    + e0.y; v = fmaxf(v, ALPHA*v); q0.y = f2bf(__expf(v));
    v = bf2f((u16)(eb.y & 0xffff)) + e0.z; v = fmaxf(v, ALPHA*v); q0.z = f2bf(__expf(v));
    v = bf2f((u16)(eb.y >> 16))    + e0.w; v = fmaxf(v, ALPHA*v); q0.w = f2bf(__expf(v));
    v = bf2f((u16)(eb.z & 0xffff)) + e1.x; v = fmaxf(v, ALPHA*v); q1.x = f2bf(__expf(v));
    v = bf2f((u16)(eb.z >> 16))    + e1.y; v = fmaxf(v, ALPHA*v); q1.y = f2bf(__expf(v));
    v = bf2f((u16)(eb.w & 0xffff)) + e1.z; v = fmaxf(v, ALPHA*v); q1.z = f2bf(__expf(v));
    v = bf2f((u16)(eb.w >> 16))    + e1.w; v = fmaxf(v, ALPHA*v); q1.w = f2bf(__expf(v));
    *(ushort4*)&wlds[lane*NH]     = q0;
    *(ushort4*)&wlds[lane*NH + 4] = q1;
  }
  __builtin_amdgcn_sched_barrier(0);   // keep ds_writes before ds_reads
  // ---- phase B: aggregation, 2 edges/iteration ----
  #pragma unroll 8
  for(int k=0; k<lim; k+=2){
    int sel = k + half;
    int sidx = __shfl(myIdx, sel, 64);
    int selc = sel < lim ? sel : 0;
    float w = bf2f(wlds[selc*NH + h]);
    if(sel >= lim) w = 0.f;
    uint4 rv = *(const uint4*)&feat16[((unsigned)sidx<<8) + col8];
    f32x2 w2 = {w, w};
    f32x2 p0 = { __uint_as_float(rv.x << 16), __uint_as_float(rv.x & 0xffff0000u) };
    f32x2 p1 = { __uint_as_float(rv.y << 16), __uint_as_float(rv.y & 0xffff0000u) };
    f32x2 p2 = { __uint_as_float(rv.z << 16), __uint_as_float(rv.z & 0xffff0000u) };
    f32x2 p3 = { __uint_as_float(rv.w << 16), __uint_as_float(rv.w & 0xffff0000u) };
    s += w;
    A2[0] += w2*p0; A2[1] += w2*p1; A2[2] += w2*p2; A2[3] += w2*p3;
  }
  A[0]=A2[0].x; A[1]=A2[0].y; A[2]=A2[1].x; A[3]=A2[1].y;
  A[4]=A2[2].x; A[5]=A2[2].y; A[6]=A2[3].x; A[7]=A2[3].y;
  s += __shfl_xor(s, 32, 64);
  #pragma unroll
  for(int j=0;j<8;j++) A[j] += __shfl_xor(A[j], 32, 64);
  float inv = 1.f/fmaxf(s, 1e-9f);
  #pragma unroll
  for(int j=0;j<8;j++) A[j] *= inv;
}

// ---------- layer 1 finalize: + b1 + x@resW1, ELU -> h1b (bf16) ----------
__global__ void k_gat1(const u16* __restrict__ feat16,
    const u16* __restrict__ elb, const float* __restrict__ er,
    const int* __restrict__ cnt, const u16* __restrict__ buck,
    const float* __restrict__ x,
    const float* __restrict__ resW1, const float* __restrict__ b1,
    u16* __restrict__ h1b){
  __shared__ u16 wsh[4*64*NH];
  int n = blockIdx.x*4 + (threadIdx.x>>6);
  int lane = threadIdx.x & 63;
  if(n>=NN) return;
  u16* wlds = wsh + (threadIdx.x>>6)*64*NH;
  float A[8];
  gat_aggw(n,lane,wlds,feat16,elb,er,cnt,buck,A);
  int half = lane>>5, l = lane&31;
  int col8 = l<<3;
  float r[8];
  #pragma unroll
  for(int j=0;j<8;j++) r[j]=0.f;
  const float* xrow = x + (size_t)n*IN_F;
  int kb = half*15;
  #pragma unroll
  for(int k=0;k<15;k++){
    float xv = xrow[kb+k];
    const float4 w0 = *(const float4*)&resW1[(kb+k)*HD + col8];
    const float4 w1 = *(const float4*)&resW1[(kb+k)*HD + col8 + 4];
    r[0]+=xv*w0.x; r[1]+=xv*w0.y; r[2]+=xv*w0.z; r[3]+=xv*w0.w;
    r[4]+=xv*w1.x; r[5]+=xv*w1.y; r[6]+=xv*w1.z; r[7]+=xv*w1.w;
  }
  #pragma unroll
  for(int j=0;j<8;j++) r[j] += __shfl_xor(r[j], 32, 64);
  if(half==0){
    const float4 b0 = *(const float4*)&b1[col8];
    const float4 b4 = *(const float4*)&b1[col8+4];
    float v; ushort4 q0, q1;
    v = A[0]+r[0]+b0.x; q0.x = f2bf((v>0.f)? v : expf(v)-1.f);
    v = A[1]+r[1]+b0.y; q0.y = f2bf((v>0.f)? v : expf(v)-1.f);
    v = A[2]+r[2]+b0.z; q0.z = f2bf((v>0.f)? v : expf(v)-1.f);
    v = A[3]+r[3]+b0.w; q0.w = f2bf((v>0.f)? v : expf(v)-1.f);
    v = A[4]+r[4]+b4.x; q1.x = f2bf((v>0.f)? v : expf(v)-1.f);
    v = A[5]+r[5]+b4.y; q1.y = f2bf((v>0.f)? v : expf(v)-1.f);
    v = A[6]+r[6]+b4.z; q1.z = f2bf((v>0.f)? v : expf(v)-1.f);
    v = A[7]+r[7]+b4.w; q1.w = f2bf((v>0.f)? v : expf(v)-1.f);
    *(ushort4*)&h1b[(size_t)n*HD + col8]     = q0;
    *(ushort4*)&h1b[(size_t)n*HD + col8 + 4] = q1;
  }
}

// ---------- layer 2 finalize: + b2 + h1b residual, mean over heads -> h2 ----------
__global__ void k_gat2(const u16* __restrict__ feat16,
    const u16* __restrict__ elb, const float* __restrict__ er,
    const int* __restrict__ cnt, const u16* __restrict__ buck,
    const u16* __restrict__ h1b,
    const float* __restrict__ b2, float* __restrict__ h2){
  __shared__ u16 wsh[4*64*NH];
  int n = blockIdx.x*4 + (threadIdx.x>>6);
  int lane = threadIdx.x & 63;
  if(n>=NN) return;
  u16* wlds = wsh + (threadIdx.x>>6)*64*NH;
  float A[8];
  gat_aggw(n,lane,wlds,feat16,elb,er,cnt,buck,A);
  int l = lane&31;
  int col8 = l<<3;
  if(lane<32){
    const float4 b0 = *(const float4*)&b2[col8];
    const float4 b4 = *(const float4*)&b2[col8+4];
    float4 h0 = bf4_to_f4(*(const ushort4*)&h1b[(size_t)n*HD + col8]);
    float4 h4 = bf4_to_f4(*(const ushort4*)&h1b[(size_t)n*HD + col8 + 4]);
    float t[8];
    t[0]=A[0]+b0.x+h0.x; t[1]=A[1]+b0.y+h0.y; t[2]=A[2]+b0.z+h0.z; t[3]=A[3]+b0.w+h0.w;
    t[4]=A[4]+b4.x+h4.x; t[5]=A[5]+b4.y+h4.y; t[6]=A[6]+b4.z+h4.z; t[7]=A[7]+b4.w+h4.w;
    // head-sum: lane l = h*4+p; reduce over h bits (offsets 4,8,16)
    #pragma unroll
    for(int off=4; off<32; off<<=1){
      #pragma unroll
      for(int j=0;j<8;j++) t[j] += __shfl_xor(t[j], off, 64);
    }
    if(l<4){
      float4 o0, o1;
      o0.x=t[0]*0.125f; o0.y=t[1]*0.125f; o0.z=t[2]*0.125f; o0.w=t[3]*0.125f;
      o1.x=t[4]*0.125f; o1.y=t[5]*0.125f; o1.z=t[6]*0.125f; o1.w=t[7]*0.125f;
      *(float4*)&h2[(size_t)n*DH + (l<<3)]     = o0;
      *(float4*)&h2[(size_t)n*DH + (l<<3) + 4] = o1;
    }
  }
}

// ---------- segmented readout + fused gate + FUSED MLP (one block per graph) ----------
__global__ void k_readout(const float* __restrict__ h2, const float* __restrict__ Ww,
    const float* __restrict__ bw, const int* __restrict__ gstart,
    const float* __restrict__ Wp1, const float* __restrict__ bp1,
    const float* __restrict__ gamma, const float* __restrict__ beta,
    const float* __restrict__ rm, const float* __restrict__ rv,
    const float* __restrict__ Wp2, const float* __restrict__ bp2,
    float* __restrict__ out){
  __shared__ float ssum[8][DH];
  __shared__ float smax[8][DH];
  __shared__ float gs[2*DH];
  __shared__ float red[NHID];
  int g = blockIdx.x;
  int t = threadIdx.x;
  int half = (t & 63) >> 5;
  int wid = t >> 6;
  int l = t & 31;
  int rg = wid*2 + half;               // row group 0..7
  int s = gstart[g], cnt = gstart[g+1] - s;
  float w_d = Ww[l];
  float bw0 = bw[0];
  float sum = 0.f, mx = -INFINITY;
  for(int r = rg; r < cnt; r += 8){
    float v = h2[(size_t)(s+r)*DH + l];
    float p = v*w_d;
    p += __shfl_xor(p,1,64); p += __shfl_xor(p,2,64); p += __shfl_xor(p,4,64);
    p += __shfl_xor(p,8,64); p += __shfl_xor(p,16,64);
    float wg = 1.f/(1.f+__expf(-(p+bw0)));
    sum += wg*v;
    mx = fmaxf(mx, v);
  }
  ssum[rg][l] = sum;
  smax[rg][l] = mx;
  __syncthreads();
  if(t < DH){
    float a = 0.f, m = -INFINITY;
    #pragma unroll
    for(int r=0;r<8;r++){ a += ssum[r][t]; m = fmaxf(m, smax[r][t]); }
    gs[t]      = a;
    gs[DH + t] = isfinite(m)? m : 0.f;   // empty-segment guard
  }
  __syncthreads();
  // MLP: hidden unit t (t < 128)
  if(t < NHID){
    float acc = bp1[t];
    #pragma unroll
    for(int k=0;k<2*DH;k++) acc += gs[k]*Wp1[k*NHID + t];
    acc = fmaxf(acc, 0.f);
    acc = (acc - rm[t])*rsqrtf(rv[t]+1e-5f)*gamma[t] + beta[t];
    red[t] = acc*Wp2[t];
  }
  __syncthreads();
  for(int off=NHID/2; off>0; off>>=1){
    if(t<off) red[t] += red[t+off];
    __syncthreads();
  }
  if(t==0) out[g] = red[0] + bp2[0];
}

extern "C" void kernel_launch(void* const* d_in, const int* in_sizes, int n_in,
                              void* d_out, int out_size, void* d_ws, size_t ws_size,
                              hipStream_t stream){
  const float* x    = (const float*)d_in[0];
  const int*   src  = (const int*)  d_in[1];
  const int*   dst  = (const int*)  d_in[2];
  const int*   gid  = (const int*)  d_in[3];
  const float* W1   = (const float*)d_in[4];
  const float* al1  = (const float*)d_in[5];
  const float* ar1  = (const float*)d_in[6];
  const float* b1   = (const float*)d_in[7];
  const float* resW1= (const float*)d_in[8];
  const float* W2   = (const float*)d_in[9];
  const float* al2  = (const float*)d_in[10];
  const float* ar2  = (const float*)d_in[11];
  const float* b2   = (const float*)d_in[12];
  const float* Ww   = (const float*)d_in[13];
  const float* bw   = (const float*)d_in[14];
  const float* Wp1  = (const float*)d_in[15];
  const float* bp1  = (const float*)d_in[16];
  const float* gamma= (const float*)d_in[17];
  const float* beta = (const float*)d_in[18];
  const float* rm   = (const float*)d_in[19];
  const float* rv   = (const float*)d_in[20];
  const float* Wp2  = (const float*)d_in[21];
  const float* bp2  = (const float*)d_in[22];
  float* out = (float*)d_out;

  char* w = (char*)d_ws;
  u16*      feat16 = (u16*)w;      w += (size_t)NN*HD*2;
  u16*      h1b    = (u16*)w;      w += (size_t)NN*HD*2;
  u16*      W2T    = (u16*)w;      w += (size_t)HD*HD*2;
  u16*      elb    = (u16*)w;      w += (size_t)NN*NH*2;
  float*    er     = (float*)w;    w += (size_t)NN*NH*4;
  float*    h2     = (float*)w;    w += (size_t)NN*DH*4;
  int*      cnt    = (int*)w;      w += (size_t)NN*4;
  int*      gstart = (int*)w;      w += (size_t)(NG+1)*4;
  u16*      buck   = (u16*)w;      w += (size_t)NN*CAP*2;

  hipMemsetAsync(cnt, 0, (size_t)NN*4, stream);
  hipLaunchKernelGGL(k_scatter,  dim3(SCB + GB),        dim3(256), 0, stream, dst, src, gid, cnt, buck, gstart);
  hipLaunchKernelGGL(k_proj1w,   dim3(P1B + 256),       dim3(256), 0, stream, x, W1, feat16, W2, W2T, al1, ar1, elb, er);
  hipLaunchKernelGGL(k_gat1,     dim3((NN+3)/4),        dim3(256), 0, stream, feat16, elb, er, cnt, buck, x, resW1, b1, h1b);
  hipLaunchKernelGGL(k_proj2m,   dim3((NN+63)/64),      dim3(256), 0, stream, h1b, W2T, feat16, al2, ar2, elb, er);
  hipLaunchKernelGGL(k_gat2,     dim3((NN+3)/4),        dim3(256), 0, stream, feat16, elb, er, cnt, buck, h1b, b2, h2);
  hipLaunchKernelGGL(k_readout,  dim3(NG),              dim3(256), 0, stream, h2, Ww, bw, gstart, Wp1, bp1, gamma, beta, rm, rv, Wp2, bp2, out);
}

// Round 9
// 408.318 us; speedup vs baseline: 1.0178x; 1.0178x over previous
//
#include <hip/hip_runtime.h>
#include <math.h>

#define NN 50000
#define EE 800000
#define IN_F 30
#define NH 8
#define DH 32
#define HD 256      // NH*DH
#define NG 512
#define NHID 128
#define ALPHA 0.2f
#define CAP 64      // fixed bucket capacity; P(Poisson(16)>64) ~ 1e-19, guarded
#define ROWB 136    // bucket row: [cnt:4B][64 x u16 slots] = 132, pad to 136 (8-aligned)

#define P1B (NN/16)                           // proj1 blocks (3125)
#define SCB ((EE+255)/256)                    // scatter blocks (3125)
#define GB  ((NN+255)/256)                    // boundary blocks (196)

typedef unsigned short u16;
typedef __attribute__((ext_vector_type(8))) short bf16x8;
typedef __attribute__((ext_vector_type(4))) float f32x4;
typedef __attribute__((ext_vector_type(2))) float f32x2;

// ---------- bf16 helpers (round-to-nearest-even) ----------
__device__ __forceinline__ u16 f2bf(float f){
  unsigned u = __float_as_uint(f);
  u = u + 0x7FFFu + ((u >> 16) & 1u);
  return (u16)(u >> 16);
}
__device__ __forceinline__ float bf2f(u16 b){
  return __uint_as_float(((unsigned)b) << 16);
}
__device__ __forceinline__ float4 bf4_to_f4(ushort4 v){
  float4 r; r.x=bf2f(v.x); r.y=bf2f(v.y); r.z=bf2f(v.z); r.w=bf2f(v.w); return r;
}

// ---------- bucket scatter + gstart from sorted gid ----------
// Embedded-counter rows: atomic on row header and the slot store hit the SAME
// 64-128B region (slot byte = 4+2p, p~0..16) -> one random line-touch per edge
// instead of two (R8 post-mortem: scatter cost = line-touches, not bytes).
// blocks [0,SCB): p = atomicAdd(rowhdr); row.slot[p] = (u16)src
// blocks [SCB,SCB+GB): graph segment starts via boundary detection (no atomics)
__global__ void k_scatter(const int* __restrict__ dst, const int* __restrict__ src,
                          const int* __restrict__ gid,
                          char* __restrict__ buck, int* __restrict__ gstart){
  int bid = blockIdx.x;
  if(bid < SCB){
    int i = bid*256 + threadIdx.x;
    if(i<EE){
      int d = dst[i];
      char* row = buck + (size_t)d*ROWB;
      int p = atomicAdd((int*)row, 1);
      if(p<CAP) ((u16*)row)[2+p] = (u16)src[i];
    }
    return;
  }
  int i = (bid-SCB)*256 + threadIdx.x;
  if(i<NN){
    int g  = gid[i];
    int gp = (i>0)? gid[i-1] : -1;
    for(int gg=gp+1; gg<=g; gg++) gstart[gg]=i;   // total writes over grid = NG
    if(i==NN-1){
      for(int gg=g+1; gg<=NG; gg++) gstart[gg]=NN;
    }
  }
}

// ---------- layer-1 projection + FUSED el1/er1 epilogue + W2 transpose tail ----
#define TM1 16
__global__ void k_proj1w(const float* __restrict__ x, const float* __restrict__ W1,
                         u16* __restrict__ feat16, const float* __restrict__ W2,
                         u16* __restrict__ W2T,
                         const float* __restrict__ al, const float* __restrict__ ar,
                         u16* __restrict__ elb, float* __restrict__ er){
  if(blockIdx.x >= P1B){                       // W2T tail: 256 blocks
    int i = (blockIdx.x - P1B)*256 + threadIdx.x;   // < HD*HD
    int n = i >> 8, k = i & 255;
    W2T[i] = f2bf(W2[k*HD + n]);
    return;                                    // block-uniform exit (no barrier crossed)
  }
  __shared__ float xs[TM1][IN_F];
  int n0 = blockIdx.x*TM1;
  int t = threadIdx.x;
  for(int i=t;i<TM1*IN_F;i+=256){
    int m=i/IN_F, k=i-m*IN_F;
    xs[m][k] = x[(size_t)(n0+m)*IN_F+k];
  }
  __syncthreads();
  int L = t & 63;
  int jq = L << 2;
  int m0 = t >> 6;
  float4 acc[4];
  #pragma unroll
  for(int r=0;r<4;r++){ acc[r].x=0.f; acc[r].y=0.f; acc[r].z=0.f; acc[r].w=0.f; }
  for(int k=0;k<IN_F;k++){
    float4 w = *(const float4*)&W1[k*HD + jq];
    #pragma unroll
    for(int r=0;r<4;r++){
      float xv = xs[m0 + (r<<2)][k];
      acc[r].x += xv*w.x; acc[r].y += xv*w.y; acc[r].z += xv*w.z; acc[r].w += xv*w.w;
    }
  }
  #pragma unroll
  for(int r=0;r<4;r++){
    int n = n0 + m0 + (r<<2);
    ushort4 o; o.x=f2bf(acc[r].x); o.y=f2bf(acc[r].y); o.z=f2bf(acc[r].z); o.w=f2bf(acc[r].w);
    *(ushort4*)&feat16[(size_t)n*HD + jq] = o;
  }
  // ---- fused el/er from f32 accumulators (el stored bf16) ----
  int h = L >> 3;
  float4 av = *(const float4*)&al[jq];
  float4 rv = *(const float4*)&ar[jq];
  #pragma unroll
  for(int r=0;r<4;r++){
    float pe = acc[r].x*av.x + acc[r].y*av.y + acc[r].z*av.z + acc[r].w*av.w;
    float pr = acc[r].x*rv.x + acc[r].y*rv.y + acc[r].z*rv.z + acc[r].w*rv.w;
    #pragma unroll
    for(int off=1; off<8; off<<=1){
      pe += __shfl_xor(pe, off, 64);
      pr += __shfl_xor(pr, off, 64);
    }
    if((L & 7) == 0){
      int n = n0 + m0 + (r<<2);
      elb[(size_t)n*NH + h] = f2bf(pe);
      er[(size_t)n*NH + h]  = pr;
    }
  }
}

// ---------- layer-2 projection via MFMA + el2/er2 epilogue ----------
__global__ void k_proj2m(const u16* __restrict__ h1b, const u16* __restrict__ W2T,
                         u16* __restrict__ Y16,
                         const float* __restrict__ al, const float* __restrict__ ar,
                         u16* __restrict__ elb, float* __restrict__ er){
  int t = threadIdx.x;
  int wave = t>>6, lane = t&63;
  int m0 = blockIdx.x*64 + wave*16;
  int lm = lane & 15, lq = lane >> 4;
  int arow = m0 + lm; if(arow >= NN) arow = NN-1;   // clamp (stores guarded)
  const u16* Aptr = h1b + (size_t)arow*HD + lq*8;
  f32x4 acc[16];
  #pragma unroll
  for(int ct=0;ct<16;ct++) acc[ct] = (f32x4){0.f,0.f,0.f,0.f};
  #pragma unroll
  for(int k0=0;k0<HD;k0+=32){
    bf16x8 a = *(const bf16x8*)(Aptr + k0);
    #pragma unroll
    for(int ct=0;ct<16;ct++){
      bf16x8 b = *(const bf16x8*)(W2T + (size_t)(ct*16 + lm)*HD + k0 + lq*8);
      acc[ct] = __builtin_amdgcn_mfma_f32_16x16x32_bf16(a, b, acc[ct], 0, 0, 0);
    }
  }
  int orow0 = m0 + lq*4;
  #pragma unroll
  for(int ct=0;ct<16;ct++){
    #pragma unroll
    for(int r=0;r<4;r++){
      int n = orow0 + r;
      if(n < NN) Y16[(size_t)n*HD + ct*16 + lm] = f2bf(acc[ct][r]);
    }
  }
  // ---- fused el/er from f32 accumulators ----
  #pragma unroll
  for(int h=0;h<NH;h++){
    float av0 = al[h*DH + lm],      rv0 = ar[h*DH + lm];
    float av1 = al[h*DH + 16 + lm], rv1 = ar[h*DH + 16 + lm];
    #pragma unroll
    for(int r=0;r<4;r++){
      float pe = acc[2*h][r]*av0 + acc[2*h+1][r]*av1;
      float pr = acc[2*h][r]*rv0 + acc[2*h+1][r]*rv1;
      #pragma unroll
      for(int off=1; off<16; off<<=1){
        pe += __shfl_xor(pe, off, 64);
        pr += __shfl_xor(pr, off, 64);
      }
      if(lm == 0){
        int n = orow0 + r;
        if(n < NN){
          elb[(size_t)n*NH + h] = f2bf(pe);
          er[(size_t)n*NH + h]  = pr;
        }
      }
    }
  }
}

// ---------- per-node softmax aggregation, single 64-edge bucket chunk ----------
// Phase A: lane computes 8-head weights for its own edge -> LDS (16B).
// Phase B: aggregation reads w from LDS. Wave-synchronous (no __syncthreads).
__device__ __forceinline__ void gat_aggw(int n, int lane, u16* wlds,
    const u16* __restrict__ feat16,
    const u16* __restrict__ elb, const float* __restrict__ er,
    const char* __restrict__ buck, float* A){
  int half = lane >> 5;
  int l = lane & 31;
  int h = l >> 2;
  int col8 = l << 3;
  const char* row = buck + (size_t)n*ROWB;
  int cnt = *(const int*)row;
  int lim = cnt < CAP ? cnt : CAP;
  const u16* slots = ((const u16*)row) + 2;
  float4 e0 = *(const float4*)&er[(size_t)n*NH];
  float4 e1 = *(const float4*)&er[(size_t)n*NH + 4];
  float s = 0.f;
  f32x2 A2[4];
  #pragma unroll
  for(int j=0;j<4;j++) A2[j]=(f32x2){0.f,0.f};
  int myIdx = (int)slots[lane < lim ? lane : (lim>0? lim-1 : 0)];
  // ---- phase A: weights for edge (base+lane), all 8 heads -> LDS ----
  if(lane < lim){
    uint4 eb = *(const uint4*)&elb[(size_t)myIdx*NH];   // 8 bf16
    float v; ushort4 q0, q1;
    v = bf2f((u16)(eb.x & 0xffff)) + e0.x; v = fmaxf(v, ALPHA*v); q0.x = f2bf(__expf(v));
    v = bf2f((u16)(eb.x >> 16))    + e0.y; v = fmaxf(v, ALPHA*v); q0.y = f2bf(__expf(v));
    v = bf2f((u16)(eb.y & 0xffff)) + e0.z; v = fmaxf(v, ALPHA*v); q0.z = f2bf(__expf(v));
    v = bf2f((u16)(eb.y >> 16))    + e0.w; v = fmaxf(v, ALPHA*v); q0.w = f2bf(__expf(v));
    v = bf2f((u16)(eb.z & 0xffff)) + e1.x; v = fmaxf(v, ALPHA*v); q1.x = f2bf(__expf(v));
    v = bf2f((u16)(eb.z >> 16))    + e1.y; v = fmaxf(v, ALPHA*v); q1.y = f2bf(__expf(v));
    v = bf2f((u16)(eb.w & 0xffff)) + e1.z; v = fmaxf(v, ALPHA*v); q1.z = f2bf(__expf(v));
    v = bf2f((u16)(eb.w >> 16))    + e1.w; v = fmaxf(v, ALPHA*v); q1.w = f2bf(__expf(v));
    *(ushort4*)&wlds[lane*NH]     = q0;
    *(ushort4*)&wlds[lane*NH + 4] = q1;
  }
  __builtin_amdgcn_sched_barrier(0);   // keep ds_writes before ds_reads
  // ---- phase B: aggregation, 2 edges/iteration ----
  #pragma unroll 8
  for(int k=0; k<lim; k+=2){
    int sel = k + half;
    int sidx = __shfl(myIdx, sel, 64);
    int selc = sel < lim ? sel : 0;
    float w = bf2f(wlds[selc*NH + h]);
    if(sel >= lim) w = 0.f;
    uint4 rv = *(const uint4*)&feat16[((unsigned)sidx<<8) + col8];
    f32x2 w2 = {w, w};
    f32x2 p0 = { __uint_as_float(rv.x << 16), __uint_as_float(rv.x & 0xffff0000u) };
    f32x2 p1 = { __uint_as_float(rv.y << 16), __uint_as_float(rv.y & 0xffff0000u) };
    f32x2 p2 = { __uint_as_float(rv.z << 16), __uint_as_float(rv.z & 0xffff0000u) };
    f32x2 p3 = { __uint_as_float(rv.w << 16), __uint_as_float(rv.w & 0xffff0000u) };
    s += w;
    A2[0] += w2*p0; A2[1] += w2*p1; A2[2] += w2*p2; A2[3] += w2*p3;
  }
  A[0]=A2[0].x; A[1]=A2[0].y; A[2]=A2[1].x; A[3]=A2[1].y;
  A[4]=A2[2].x; A[5]=A2[2].y; A[6]=A2[3].x; A[7]=A2[3].y;
  s += __shfl_xor(s, 32, 64);
  #pragma unroll
  for(int j=0;j<8;j++) A[j] += __shfl_xor(A[j], 32, 64);
  float inv = 1.f/fmaxf(s, 1e-9f);
  #pragma unroll
  for(int j=0;j<8;j++) A[j] *= inv;
}

// ---------- layer 1 finalize: + b1 + x@resW1, ELU -> h1b (bf16) ----------
__global__ void k_gat1(const u16* __restrict__ feat16,
    const u16* __restrict__ elb, const float* __restrict__ er,
    const char* __restrict__ buck,
    const float* __restrict__ x,
    const float* __restrict__ resW1, const float* __restrict__ b1,
    u16* __restrict__ h1b){
  __shared__ u16 wsh[4*64*NH];
  int n = blockIdx.x*4 + (threadIdx.x>>6);
  int lane = threadIdx.x & 63;
  if(n>=NN) return;
  u16* wlds = wsh + (threadIdx.x>>6)*64*NH;
  float A[8];
  gat_aggw(n,lane,wlds,feat16,elb,er,buck,A);
  int half = lane>>5, l = lane&31;
  int col8 = l<<3;
  float r[8];
  #pragma unroll
  for(int j=0;j<8;j++) r[j]=0.f;
  const float* xrow = x + (size_t)n*IN_F;
  int kb = half*15;
  #pragma unroll
  for(int k=0;k<15;k++){
    float xv = xrow[kb+k];
    const float4 w0 = *(const float4*)&resW1[(kb+k)*HD + col8];
    const float4 w1 = *(const float4*)&resW1[(kb+k)*HD + col8 + 4];
    r[0]+=xv*w0.x; r[1]+=xv*w0.y; r[2]+=xv*w0.z; r[3]+=xv*w0.w;
    r[4]+=xv*w1.x; r[5]+=xv*w1.y; r[6]+=xv*w1.z; r[7]+=xv*w1.w;
  }
  #pragma unroll
  for(int j=0;j<8;j++) r[j] += __shfl_xor(r[j], 32, 64);
  if(half==0){
    const float4 b0 = *(const float4*)&b1[col8];
    const float4 b4 = *(const float4*)&b1[col8+4];
    float v; ushort4 q0, q1;
    v = A[0]+r[0]+b0.x; q0.x = f2bf((v>0.f)? v : expf(v)-1.f);
    v = A[1]+r[1]+b0.y; q0.y = f2bf((v>0.f)? v : expf(v)-1.f);
    v = A[2]+r[2]+b0.z; q0.z = f2bf((v>0.f)? v : expf(v)-1.f);
    v = A[3]+r[3]+b0.w; q0.w = f2bf((v>0.f)? v : expf(v)-1.f);
    v = A[4]+r[4]+b4.x; q1.x = f2bf((v>0.f)? v : expf(v)-1.f);
    v = A[5]+r[5]+b4.y; q1.y = f2bf((v>0.f)? v : expf(v)-1.f);
    v = A[6]+r[6]+b4.z; q1.z = f2bf((v>0.f)? v : expf(v)-1.f);
    v = A[7]+r[7]+b4.w; q1.w = f2bf((v>0.f)? v : expf(v)-1.f);
    *(ushort4*)&h1b[(size_t)n*HD + col8]     = q0;
    *(ushort4*)&h1b[(size_t)n*HD + col8 + 4] = q1;
  }
}

// ---------- layer 2 finalize: + b2 + h1b residual, mean over heads -> h2 ----------
__global__ void k_gat2(const u16* __restrict__ feat16,
    const u16* __restrict__ elb, const float* __restrict__ er,
    const char* __restrict__ buck,
    const u16* __restrict__ h1b,
    const float* __restrict__ b2, float* __restrict__ h2){
  __shared__ u16 wsh[4*64*NH];
  int n = blockIdx.x*4 + (threadIdx.x>>6);
  int lane = threadIdx.x & 63;
  if(n>=NN) return;
  u16* wlds = wsh + (threadIdx.x>>6)*64*NH;
  float A[8];
  gat_aggw(n,lane,wlds,feat16,elb,er,buck,A);
  int l = lane&31;
  int col8 = l<<3;
  if(lane<32){
    const float4 b0 = *(const float4*)&b2[col8];
    const float4 b4 = *(const float4*)&b2[col8+4];
    float4 h0 = bf4_to_f4(*(const ushort4*)&h1b[(size_t)n*HD + col8]);
    float4 h4 = bf4_to_f4(*(const ushort4*)&h1b[(size_t)n*HD + col8 + 4]);
    float t[8];
    t[0]=A[0]+b0.x+h0.x; t[1]=A[1]+b0.y+h0.y; t[2]=A[2]+b0.z+h0.z; t[3]=A[3]+b0.w+h0.w;
    t[4]=A[4]+b4.x+h4.x; t[5]=A[5]+b4.y+h4.y; t[6]=A[6]+b4.z+h4.z; t[7]=A[7]+b4.w+h4.w;
    // head-sum: lane l = h*4+p; reduce over h bits (offsets 4,8,16)
    #pragma unroll
    for(int off=4; off<32; off<<=1){
      #pragma unroll
      for(int j=0;j<8;j++) t[j] += __shfl_xor(t[j], off, 64);
    }
    if(l<4){
      float4 o0, o1;
      o0.x=t[0]*0.125f; o0.y=t[1]*0.125f; o0.z=t[2]*0.125f; o0.w=t[3]*0.125f;
      o1.x=t[4]*0.125f; o1.y=t[5]*0.125f; o1.z=t[6]*0.125f; o1.w=t[7]*0.125f;
      *(float4*)&h2[(size_t)n*DH + (l<<3)]     = o0;
      *(float4*)&h2[(size_t)n*DH + (l<<3) + 4] = o1;
    }
  }
}

// ---------- segmented readout + fused gate + FUSED MLP (one block per graph) ----------
__global__ void k_readout(const float* __restrict__ h2, const float* __restrict__ Ww,
    const float* __restrict__ bw, const int* __restrict__ gstart,
    const float* __restrict__ Wp1, const float* __restrict__ bp1,
    const float* __restrict__ gamma, const float* __restrict__ beta,
    const float* __restrict__ rm, const float* __restrict__ rv,
    const float* __restrict__ Wp2, const float* __restrict__ bp2,
    float* __restrict__ out){
  __shared__ float ssum[8][DH];
  __shared__ float smax[8][DH];
  __shared__ float gs[2*DH];
  __shared__ float red[NHID];
  int g = blockIdx.x;
  int t = threadIdx.x;
  int half = (t & 63) >> 5;
  int wid = t >> 6;
  int l = t & 31;
  int rg = wid*2 + half;               // row group 0..7
  int s = gstart[g], cnt = gstart[g+1] - s;
  float w_d = Ww[l];
  float bw0 = bw[0];
  float sum = 0.f, mx = -INFINITY;
  for(int r = rg; r < cnt; r += 8){
    float v = h2[(size_t)(s+r)*DH + l];
    float p = v*w_d;
    p += __shfl_xor(p,1,64); p += __shfl_xor(p,2,64); p += __shfl_xor(p,4,64);
    p += __shfl_xor(p,8,64); p += __shfl_xor(p,16,64);
    float wg = 1.f/(1.f+__expf(-(p+bw0)));
    sum += wg*v;
    mx = fmaxf(mx, v);
  }
  ssum[rg][l] = sum;
  smax[rg][l] = mx;
  __syncthreads();
  if(t < DH){
    float a = 0.f, m = -INFINITY;
    #pragma unroll
    for(int r=0;r<8;r++){ a += ssum[r][t]; m = fmaxf(m, smax[r][t]); }
    gs[t]      = a;
    gs[DH + t] = isfinite(m)? m : 0.f;   // empty-segment guard
  }
  __syncthreads();
  // MLP: hidden unit t (t < 128)
  if(t < NHID){
    float acc = bp1[t];
    #pragma unroll
    for(int k=0;k<2*DH;k++) acc += gs[k]*Wp1[k*NHID + t];
    acc = fmaxf(acc, 0.f);
    acc = (acc - rm[t])*rsqrtf(rv[t]+1e-5f)*gamma[t] + beta[t];
    red[t] = acc*Wp2[t];
  }
  __syncthreads();
  for(int off=NHID/2; off>0; off>>=1){
    if(t<off) red[t] += red[t+off];
    __syncthreads();
  }
  if(t==0) out[g] = red[0] + bp2[0];
}

extern "C" void kernel_launch(void* const* d_in, const int* in_sizes, int n_in,
                              void* d_out, int out_size, void* d_ws, size_t ws_size,
                              hipStream_t stream){
  const float* x    = (const float*)d_in[0];
  const int*   src  = (const int*)  d_in[1];
  const int*   dst  = (const int*)  d_in[2];
  const int*   gid  = (const int*)  d_in[3];
  const float* W1   = (const float*)d_in[4];
  const float* al1  = (const float*)d_in[5];
  const float* ar1  = (const float*)d_in[6];
  const float* b1   = (const float*)d_in[7];
  const float* resW1= (const float*)d_in[8];
  const float* W2   = (const float*)d_in[9];
  const float* al2  = (const float*)d_in[10];
  const float* ar2  = (const float*)d_in[11];
  const float* b2   = (const float*)d_in[12];
  const float* Ww   = (const float*)d_in[13];
  const float* bw   = (const float*)d_in[14];
  const float* Wp1  = (const float*)d_in[15];
  const float* bp1  = (const float*)d_in[16];
  const float* gamma= (const float*)d_in[17];
  const float* beta = (const float*)d_in[18];
  const float* rm   = (const float*)d_in[19];
  const float* rv   = (const float*)d_in[20];
  const float* Wp2  = (const float*)d_in[21];
  const float* bp2  = (const float*)d_in[22];
  float* out = (float*)d_out;

  char* w = (char*)d_ws;
  u16*      feat16 = (u16*)w;      w += (size_t)NN*HD*2;
  u16*      h1b    = (u16*)w;      w += (size_t)NN*HD*2;
  u16*      W2T    = (u16*)w;      w += (size_t)HD*HD*2;
  u16*      elb    = (u16*)w;      w += (size_t)NN*NH*2;
  float*    er     = (float*)w;    w += (size_t)NN*NH*4;
  float*    h2     = (float*)w;    w += (size_t)NN*DH*4;
  int*      gstart = (int*)w;      w += (size_t)(NG+1)*4;
  char*     buck   = w;            w += (size_t)NN*ROWB;

  hipMemsetAsync(buck, 0, (size_t)NN*ROWB, stream);   // zeroes embedded counters
  hipLaunchKernelGGL(k_scatter,  dim3(SCB + GB),        dim3(256), 0, stream, dst, src, gid, buck, gstart);
  hipLaunchKernelGGL(k_proj1w,   dim3(P1B + 256),       dim3(256), 0, stream, x, W1, feat16, W2, W2T, al1, ar1, elb, er);
  hipLaunchKernelGGL(k_gat1,     dim3((NN+3)/4),        dim3(256), 0, stream, feat16, elb, er, buck, x, resW1, b1, h1b);
  hipLaunchKernelGGL(k_proj2m,   dim3((NN+63)/64),      dim3(256), 0, stream, h1b, W2T, feat16, al2, ar2, elb, er);
  hipLaunchKernelGGL(k_gat2,     dim3((NN+3)/4),        dim3(256), 0, stream, feat16, elb, er, buck, h1b, b2, h2);
  hipLaunchKernelGGL(k_readout,  dim3(NG),              dim3(256), 0, stream, h2, Ww, bw, gstart, Wp1, bp1, gamma, beta, rm, rv, Wp2, bp2, out);
}

// Round 10
// 400.578 us; speedup vs baseline: 1.0375x; 1.0193x over previous
//
#include <hip/hip_runtime.h>
#include <math.h>

#define NN 50000
#define EE 800000
#define IN_F 30
#define NH 8
#define DH 32
#define HD 256      // NH*DH
#define NG 512
#define NHID 128
#define ALPHA 0.2f
#define CAP 62      // fixed bucket capacity; P(max deg > 62) ~ 1e-7, guarded
#define ROWB 128    // bucket row: [cnt:4B][62 x u16 slots] = 128 B = exactly 2 lines

#define P1B (NN/16)                           // proj1 blocks (3125)
#define SCB ((EE+255)/256)                    // scatter blocks (3125)
#define GB  ((NN+255)/256)                    // boundary blocks (196)

typedef unsigned short u16;
typedef __attribute__((ext_vector_type(8))) short bf16x8;
typedef __attribute__((ext_vector_type(4))) float f32x4;
typedef __attribute__((ext_vector_type(2))) float f32x2;

// ---------- bf16 helpers (round-to-nearest-even) ----------
__device__ __forceinline__ u16 f2bf(float f){
  unsigned u = __float_as_uint(f);
  u = u + 0x7FFFu + ((u >> 16) & 1u);
  return (u16)(u >> 16);
}
__device__ __forceinline__ float bf2f(u16 b){
  return __uint_as_float(((unsigned)b) << 16);
}
__device__ __forceinline__ float4 bf4_to_f4(ushort4 v){
  float4 r; r.x=bf2f(v.x); r.y=bf2f(v.y); r.z=bf2f(v.z); r.w=bf2f(v.w); return r;
}

// ---------- bucket scatter + gstart from sorted gid ----------
// Embedded-counter rows, 128B (2-line) aligned: atomic on row header and the
// slot store hit the SAME line for p<=29 (slot byte = 4+2p).
__global__ void k_scatter(const int* __restrict__ dst, const int* __restrict__ src,
                          const int* __restrict__ gid,
                          char* __restrict__ buck, int* __restrict__ gstart){
  int bid = blockIdx.x;
  if(bid < SCB){
    int i = bid*256 + threadIdx.x;
    if(i<EE){
      int d = dst[i];
      char* row = buck + (size_t)d*ROWB;
      int p = atomicAdd((int*)row, 1);
      if(p<CAP) ((u16*)row)[2+p] = (u16)src[i];
    }
    return;
  }
  int i = (bid-SCB)*256 + threadIdx.x;
  if(i<NN){
    int g  = gid[i];
    int gp = (i>0)? gid[i-1] : -1;
    for(int gg=gp+1; gg<=g; gg++) gstart[gg]=i;   // total writes over grid = NG
    if(i==NN-1){
      for(int gg=g+1; gg<=NG; gg++) gstart[gg]=NN;
    }
  }
}

// ---------- layer-1 projection + FUSED el1/er1 epilogue + W2 transpose tail ----
#define TM1 16
__global__ void k_proj1w(const float* __restrict__ x, const float* __restrict__ W1,
                         u16* __restrict__ feat16, const float* __restrict__ W2,
                         u16* __restrict__ W2T,
                         const float* __restrict__ al, const float* __restrict__ ar,
                         u16* __restrict__ elb, float* __restrict__ er){
  if(blockIdx.x >= P1B){                       // W2T tail: 256 blocks
    int i = (blockIdx.x - P1B)*256 + threadIdx.x;   // < HD*HD
    int n = i >> 8, k = i & 255;
    W2T[i] = f2bf(W2[k*HD + n]);
    return;                                    // block-uniform exit (no barrier crossed)
  }
  __shared__ float xs[TM1][IN_F];
  int n0 = blockIdx.x*TM1;
  int t = threadIdx.x;
  for(int i=t;i<TM1*IN_F;i+=256){
    int m=i/IN_F, k=i-m*IN_F;
    xs[m][k] = x[(size_t)(n0+m)*IN_F+k];
  }
  __syncthreads();
  int L = t & 63;
  int jq = L << 2;
  int m0 = t >> 6;
  float4 acc[4];
  #pragma unroll
  for(int r=0;r<4;r++){ acc[r].x=0.f; acc[r].y=0.f; acc[r].z=0.f; acc[r].w=0.f; }
  for(int k=0;k<IN_F;k++){
    float4 w = *(const float4*)&W1[k*HD + jq];
    #pragma unroll
    for(int r=0;r<4;r++){
      float xv = xs[m0 + (r<<2)][k];
      acc[r].x += xv*w.x; acc[r].y += xv*w.y; acc[r].z += xv*w.z; acc[r].w += xv*w.w;
    }
  }
  #pragma unroll
  for(int r=0;r<4;r++){
    int n = n0 + m0 + (r<<2);
    ushort4 o; o.x=f2bf(acc[r].x); o.y=f2bf(acc[r].y); o.z=f2bf(acc[r].z); o.w=f2bf(acc[r].w);
    *(ushort4*)&feat16[(size_t)n*HD + jq] = o;
  }
  // ---- fused el/er from f32 accumulators (el stored bf16) ----
  int h = L >> 3;
  float4 av = *(const float4*)&al[jq];
  float4 rv = *(const float4*)&ar[jq];
  #pragma unroll
  for(int r=0;r<4;r++){
    float pe = acc[r].x*av.x + acc[r].y*av.y + acc[r].z*av.z + acc[r].w*av.w;
    float pr = acc[r].x*rv.x + acc[r].y*rv.y + acc[r].z*rv.z + acc[r].w*rv.w;
    #pragma unroll
    for(int off=1; off<8; off<<=1){
      pe += __shfl_xor(pe, off, 64);
      pr += __shfl_xor(pr, off, 64);
    }
    if((L & 7) == 0){
      int n = n0 + m0 + (r<<2);
      elb[(size_t)n*NH + h] = f2bf(pe);
      er[(size_t)n*NH + h]  = pr;
    }
  }
}

// ---------- layer-2 projection via MFMA + el2/er2 epilogue ----------
__global__ void k_proj2m(const u16* __restrict__ h1b, const u16* __restrict__ W2T,
                         u16* __restrict__ Y16,
                         const float* __restrict__ al, const float* __restrict__ ar,
                         u16* __restrict__ elb, float* __restrict__ er){
  int t = threadIdx.x;
  int wave = t>>6, lane = t&63;
  int m0 = blockIdx.x*64 + wave*16;
  int lm = lane & 15, lq = lane >> 4;
  int arow = m0 + lm; if(arow >= NN) arow = NN-1;   // clamp (stores guarded)
  const u16* Aptr = h1b + (size_t)arow*HD + lq*8;
  f32x4 acc[16];
  #pragma unroll
  for(int ct=0;ct<16;ct++) acc[ct] = (f32x4){0.f,0.f,0.f,0.f};
  #pragma unroll
  for(int k0=0;k0<HD;k0+=32){
    bf16x8 a = *(const bf16x8*)(Aptr + k0);
    #pragma unroll
    for(int ct=0;ct<16;ct++){
      bf16x8 b = *(const bf16x8*)(W2T + (size_t)(ct*16 + lm)*HD + k0 + lq*8);
      acc[ct] = __builtin_amdgcn_mfma_f32_16x16x32_bf16(a, b, acc[ct], 0, 0, 0);
    }
  }
  int orow0 = m0 + lq*4;
  #pragma unroll
  for(int ct=0;ct<16;ct++){
    #pragma unroll
    for(int r=0;r<4;r++){
      int n = orow0 + r;
      if(n < NN) Y16[(size_t)n*HD + ct*16 + lm] = f2bf(acc[ct][r]);
    }
  }
  // ---- fused el/er from f32 accumulators ----
  #pragma unroll
  for(int h=0;h<NH;h++){
    float av0 = al[h*DH + lm],      rv0 = ar[h*DH + lm];
    float av1 = al[h*DH + 16 + lm], rv1 = ar[h*DH + 16 + lm];
    #pragma unroll
    for(int r=0;r<4;r++){
      float pe = acc[2*h][r]*av0 + acc[2*h+1][r]*av1;
      float pr = acc[2*h][r]*rv0 + acc[2*h+1][r]*rv1;
      #pragma unroll
      for(int off=1; off<16; off<<=1){
        pe += __shfl_xor(pe, off, 64);
        pr += __shfl_xor(pr, off, 64);
      }
      if(lm == 0){
        int n = orow0 + r;
        if(n < NN){
          elb[(size_t)n*NH + h] = f2bf(pe);
          er[(size_t)n*NH + h]  = pr;
        }
      }
    }
  }
}

// ---------- per-node softmax aggregation, single bucket chunk ----------
// Phase A: lane computes 8-head weights for its own edge -> LDS (16B).
// Phase B: BATCHED aggregation — 8 edges/iteration, 4 feat rows + 4 weights
// loaded into explicit arrays BEFORE accumulation, forcing ~4 gathers in
// flight per wave-half (R10 experiment: is the 2.3 TB/s "wall" MLP-limited?).
__device__ __forceinline__ void gat_aggw(int n, int lane, u16* wlds,
    const u16* __restrict__ feat16,
    const u16* __restrict__ elb, const float* __restrict__ er,
    const char* __restrict__ buck, float* A){
  int half = lane >> 5;
  int l = lane & 31;
  int h = l >> 2;
  int col8 = l << 3;
  const char* row = buck + (size_t)n*ROWB;
  int cnt = *(const int*)row;
  int lim = cnt < CAP ? cnt : CAP;
  const u16* slots = ((const u16*)row) + 2;
  float4 e0 = *(const float4*)&er[(size_t)n*NH];
  float4 e1 = *(const float4*)&er[(size_t)n*NH + 4];
  float s = 0.f;
  f32x2 A2[4];
  #pragma unroll
  for(int j=0;j<4;j++) A2[j]=(f32x2){0.f,0.f};
  int myIdx = (int)slots[lane < lim ? lane : (lim>0? lim-1 : 0)];
  // ---- phase A: weights for edge (base+lane), all 8 heads -> LDS ----
  if(lane < lim){
    uint4 eb = *(const uint4*)&elb[(size_t)myIdx*NH];   // 8 bf16
    float v; ushort4 q0, q1;
    v = bf2f((u16)(eb.x & 0xffff)) + e0.x; v = fmaxf(v, ALPHA*v); q0.x = f2bf(__expf(v));
    v = bf2f((u16)(eb.x >> 16))    + e0.y; v = fmaxf(v, ALPHA*v); q0.y = f2bf(__expf(v));
    v = bf2f((u16)(eb.y & 0xffff)) + e0.z; v = fmaxf(v, ALPHA*v); q0.z = f2bf(__expf(v));
    v = bf2f((u16)(eb.y >> 16))    + e0.w; v = fmaxf(v, ALPHA*v); q0.w = f2bf(__expf(v));
    v = bf2f((u16)(eb.z & 0xffff)) + e1.x; v = fmaxf(v, ALPHA*v); q1.x = f2bf(__expf(v));
    v = bf2f((u16)(eb.z >> 16))    + e1.y; v = fmaxf(v, ALPHA*v); q1.y = f2bf(__expf(v));
    v = bf2f((u16)(eb.w & 0xffff)) + e1.z; v = fmaxf(v, ALPHA*v); q1.z = f2bf(__expf(v));
    v = bf2f((u16)(eb.w >> 16))    + e1.w; v = fmaxf(v, ALPHA*v); q1.w = f2bf(__expf(v));
    *(ushort4*)&wlds[lane*NH]     = q0;
    *(ushort4*)&wlds[lane*NH + 4] = q1;
  }
  __builtin_amdgcn_sched_barrier(0);   // keep ds_writes before ds_reads
  // ---- phase B: batched aggregation, 8 edges/iter (4 per half) ----
  // k0 is a multiple of 8 and k0 < lim <= 62 -> sel = k0+2j+half <= 56+7 = 63 (no shfl wrap)
  for(int k0=0; k0<lim; k0+=8){
    uint4 rv[4]; float wv[4];
    #pragma unroll
    for(int j=0;j<4;j++){
      int sel = k0 + 2*j + half;
      int sidx = __shfl(myIdx, sel, 64);
      int selc = sel < lim ? sel : 0;
      float w = bf2f(wlds[selc*NH + h]);
      wv[j] = (sel < lim) ? w : 0.f;
      rv[j] = *(const uint4*)&feat16[((unsigned)sidx<<8) + col8];
    }
    #pragma unroll
    for(int j=0;j<4;j++){
      f32x2 w2 = {wv[j], wv[j]};
      f32x2 p0 = { __uint_as_float(rv[j].x << 16), __uint_as_float(rv[j].x & 0xffff0000u) };
      f32x2 p1 = { __uint_as_float(rv[j].y << 16), __uint_as_float(rv[j].y & 0xffff0000u) };
      f32x2 p2 = { __uint_as_float(rv[j].z << 16), __uint_as_float(rv[j].z & 0xffff0000u) };
      f32x2 p3 = { __uint_as_float(rv[j].w << 16), __uint_as_float(rv[j].w & 0xffff0000u) };
      s += wv[j];
      A2[0] += w2*p0; A2[1] += w2*p1; A2[2] += w2*p2; A2[3] += w2*p3;
    }
  }
  A[0]=A2[0].x; A[1]=A2[0].y; A[2]=A2[1].x; A[3]=A2[1].y;
  A[4]=A2[2].x; A[5]=A2[2].y; A[6]=A2[3].x; A[7]=A2[3].y;
  s += __shfl_xor(s, 32, 64);
  #pragma unroll
  for(int j=0;j<8;j++) A[j] += __shfl_xor(A[j], 32, 64);
  float inv = 1.f/fmaxf(s, 1e-9f);
  #pragma unroll
  for(int j=0;j<8;j++) A[j] *= inv;
}

// ---------- layer 1 finalize: + b1 + x@resW1, ELU -> h1b (bf16) ----------
__global__ void k_gat1(const u16* __restrict__ feat16,
    const u16* __restrict__ elb, const float* __restrict__ er,
    const char* __restrict__ buck,
    const float* __restrict__ x,
    const float* __restrict__ resW1, const float* __restrict__ b1,
    u16* __restrict__ h1b){
  __shared__ u16 wsh[4*64*NH];
  int n = blockIdx.x*4 + (threadIdx.x>>6);
  int lane = threadIdx.x & 63;
  if(n>=NN) return;
  u16* wlds = wsh + (threadIdx.x>>6)*64*NH;
  float A[8];
  gat_aggw(n,lane,wlds,feat16,elb,er,buck,A);
  int half = lane>>5, l = lane&31;
  int col8 = l<<3;
  float r[8];
  #pragma unroll
  for(int j=0;j<8;j++) r[j]=0.f;
  const float* xrow = x + (size_t)n*IN_F;
  int kb = half*15;
  #pragma unroll
  for(int k=0;k<15;k++){
    float xv = xrow[kb+k];
    const float4 w0 = *(const float4*)&resW1[(kb+k)*HD + col8];
    const float4 w1 = *(const float4*)&resW1[(kb+k)*HD + col8 + 4];
    r[0]+=xv*w0.x; r[1]+=xv*w0.y; r[2]+=xv*w0.z; r[3]+=xv*w0.w;
    r[4]+=xv*w1.x; r[5]+=xv*w1.y; r[6]+=xv*w1.z; r[7]+=xv*w1.w;
  }
  #pragma unroll
  for(int j=0;j<8;j++) r[j] += __shfl_xor(r[j], 32, 64);
  if(half==0){
    const float4 b0 = *(const float4*)&b1[col8];
    const float4 b4 = *(const float4*)&b1[col8+4];
    float v; ushort4 q0, q1;
    v = A[0]+r[0]+b0.x; q0.x = f2bf((v>0.f)? v : expf(v)-1.f);
    v = A[1]+r[1]+b0.y; q0.y = f2bf((v>0.f)? v : expf(v)-1.f);
    v = A[2]+r[2]+b0.z; q0.z = f2bf((v>0.f)? v : expf(v)-1.f);
    v = A[3]+r[3]+b0.w; q0.w = f2bf((v>0.f)? v : expf(v)-1.f);
    v = A[4]+r[4]+b4.x; q1.x = f2bf((v>0.f)? v : expf(v)-1.f);
    v = A[5]+r[5]+b4.y; q1.y = f2bf((v>0.f)? v : expf(v)-1.f);
    v = A[6]+r[6]+b4.z; q1.z = f2bf((v>0.f)? v : expf(v)-1.f);
    v = A[7]+r[7]+b4.w; q1.w = f2bf((v>0.f)? v : expf(v)-1.f);
    *(ushort4*)&h1b[(size_t)n*HD + col8]     = q0;
    *(ushort4*)&h1b[(size_t)n*HD + col8 + 4] = q1;
  }
}

// ---------- layer 2 finalize: + b2 + h1b residual, mean over heads -> h2 ----------
__global__ void k_gat2(const u16* __restrict__ feat16,
    const u16* __restrict__ elb, const float* __restrict__ er,
    const char* __restrict__ buck,
    const u16* __restrict__ h1b,
    const float* __restrict__ b2, float* __restrict__ h2){
  __shared__ u16 wsh[4*64*NH];
  int n = blockIdx.x*4 + (threadIdx.x>>6);
  int lane = threadIdx.x & 63;
  if(n>=NN) return;
  u16* wlds = wsh + (threadIdx.x>>6)*64*NH;
  float A[8];
  gat_aggw(n,lane,wlds,feat16,elb,er,buck,A);
  int l = lane&31;
  int col8 = l<<3;
  if(lane<32){
    const float4 b0 = *(const float4*)&b2[col8];
    const float4 b4 = *(const float4*)&b2[col8+4];
    float4 h0 = bf4_to_f4(*(const ushort4*)&h1b[(size_t)n*HD + col8]);
    float4 h4 = bf4_to_f4(*(const ushort4*)&h1b[(size_t)n*HD + col8 + 4]);
    float t[8];
    t[0]=A[0]+b0.x+h0.x; t[1]=A[1]+b0.y+h0.y; t[2]=A[2]+b0.z+h0.z; t[3]=A[3]+b0.w+h0.w;
    t[4]=A[4]+b4.x+h4.x; t[5]=A[5]+b4.y+h4.y; t[6]=A[6]+b4.z+h4.z; t[7]=A[7]+b4.w+h4.w;
    // head-sum: lane l = h*4+p; reduce over h bits (offsets 4,8,16)
    #pragma unroll
    for(int off=4; off<32; off<<=1){
      #pragma unroll
      for(int j=0;j<8;j++) t[j] += __shfl_xor(t[j], off, 64);
    }
    if(l<4){
      float4 o0, o1;
      o0.x=t[0]*0.125f; o0.y=t[1]*0.125f; o0.z=t[2]*0.125f; o0.w=t[3]*0.125f;
      o1.x=t[4]*0.125f; o1.y=t[5]*0.125f; o1.z=t[6]*0.125f; o1.w=t[7]*0.125f;
      *(float4*)&h2[(size_t)n*DH + (l<<3)]     = o0;
      *(float4*)&h2[(size_t)n*DH + (l<<3) + 4] = o1;
    }
  }
}

// ---------- segmented readout + fused gate + FUSED MLP (one block per graph) ----------
__global__ void k_readout(const float* __restrict__ h2, const float* __restrict__ Ww,
    const float* __restrict__ bw, const int* __restrict__ gstart,
    const float* __restrict__ Wp1, const float* __restrict__ bp1,
    const float* __restrict__ gamma, const float* __restrict__ beta,
    const float* __restrict__ rm, const float* __restrict__ rv,
    const float* __restrict__ Wp2, const float* __restrict__ bp2,
    float* __restrict__ out){
  __shared__ float ssum[8][DH];
  __shared__ float smax[8][DH];
  __shared__ float gs[2*DH];
  __shared__ float red[NHID];
  int g = blockIdx.x;
  int t = threadIdx.x;
  int half = (t & 63) >> 5;
  int wid = t >> 6;
  int l = t & 31;
  int rg = wid*2 + half;               // row group 0..7
  int s = gstart[g], cnt = gstart[g+1] - s;
  float w_d = Ww[l];
  float bw0 = bw[0];
  float sum = 0.f, mx = -INFINITY;
  for(int r = rg; r < cnt; r += 8){
    float v = h2[(size_t)(s+r)*DH + l];
    float p = v*w_d;
    p += __shfl_xor(p,1,64); p += __shfl_xor(p,2,64); p += __shfl_xor(p,4,64);
    p += __shfl_xor(p,8,64); p += __shfl_xor(p,16,64);
    float wg = 1.f/(1.f+__expf(-(p+bw0)));
    sum += wg*v;
    mx = fmaxf(mx, v);
  }
  ssum[rg][l] = sum;
  smax[rg][l] = mx;
  __syncthreads();
  if(t < DH){
    float a = 0.f, m = -INFINITY;
    #pragma unroll
    for(int r=0;r<8;r++){ a += ssum[r][t]; m = fmaxf(m, smax[r][t]); }
    gs[t]      = a;
    gs[DH + t] = isfinite(m)? m : 0.f;   // empty-segment guard
  }
  __syncthreads();
  // MLP: hidden unit t (t < 128)
  if(t < NHID){
    float acc = bp1[t];
    #pragma unroll
    for(int k=0;k<2*DH;k++) acc += gs[k]*Wp1[k*NHID + t];
    acc = fmaxf(acc, 0.f);
    acc = (acc - rm[t])*rsqrtf(rv[t]+1e-5f)*gamma[t] + beta[t];
    red[t] = acc*Wp2[t];
  }
  __syncthreads();
  for(int off=NHID/2; off>0; off>>=1){
    if(t<off) red[t] += red[t+off];
    __syncthreads();
  }
  if(t==0) out[g] = red[0] + bp2[0];
}

extern "C" void kernel_launch(void* const* d_in, const int* in_sizes, int n_in,
                              void* d_out, int out_size, void* d_ws, size_t ws_size,
                              hipStream_t stream){
  const float* x    = (const float*)d_in[0];
  const int*   src  = (const int*)  d_in[1];
  const int*   dst  = (const int*)  d_in[2];
  const int*   gid  = (const int*)  d_in[3];
  const float* W1   = (const float*)d_in[4];
  const float* al1  = (const float*)d_in[5];
  const float* ar1  = (const float*)d_in[6];
  const float* b1   = (const float*)d_in[7];
  const float* resW1= (const float*)d_in[8];
  const float* W2   = (const float*)d_in[9];
  const float* al2  = (const float*)d_in[10];
  const float* ar2  = (const float*)d_in[11];
  const float* b2   = (const float*)d_in[12];
  const float* Ww   = (const float*)d_in[13];
  const float* bw   = (const float*)d_in[14];
  const float* Wp1  = (const float*)d_in[15];
  const float* bp1  = (const float*)d_in[16];
  const float* gamma= (const float*)d_in[17];
  const float* beta = (const float*)d_in[18];
  const float* rm   = (const float*)d_in[19];
  const float* rv   = (const float*)d_in[20];
  const float* Wp2  = (const float*)d_in[21];
  const float* bp2  = (const float*)d_in[22];
  float* out = (float*)d_out;

  char* w = (char*)d_ws;
  u16*      feat16 = (u16*)w;      w += (size_t)NN*HD*2;
  u16*      h1b    = (u16*)w;      w += (size_t)NN*HD*2;
  u16*      W2T    = (u16*)w;      w += (size_t)HD*HD*2;
  u16*      elb    = (u16*)w;      w += (size_t)NN*NH*2;
  float*    er     = (float*)w;    w += (size_t)NN*NH*4;
  float*    h2     = (float*)w;    w += (size_t)NN*DH*4;
  int*      gstart = (int*)w;      w += (size_t)(NG+1)*4;
  char*     buck   = w;            w += (size_t)NN*ROWB;

  hipMemsetAsync(buck, 0, (size_t)NN*ROWB, stream);   // zeroes embedded counters
  hipLaunchKernelGGL(k_scatter,  dim3(SCB + GB),        dim3(256), 0, stream, dst, src, gid, buck, gstart);
  hipLaunchKernelGGL(k_proj1w,   dim3(P1B + 256),       dim3(256), 0, stream, x, W1, feat16, W2, W2T, al1, ar1, elb, er);
  hipLaunchKernelGGL(k_gat1,     dim3((NN+3)/4),        dim3(256), 0, stream, feat16, elb, er, buck, x, resW1, b1, h1b);
  hipLaunchKernelGGL(k_proj2m,   dim3((NN+63)/64),      dim3(256), 0, stream, h1b, W2T, feat16, al2, ar2, elb, er);
  hipLaunchKernelGGL(k_gat2,     dim3((NN+3)/4),        dim3(256), 0, stream, feat16, elb, er, buck, h1b, b2, h2);
  hipLaunchKernelGGL(k_readout,  dim3(NG),              dim3(256), 0, stream, h2, Ww, bw, gstart, Wp1, bp1, gamma, beta, rm, rv, Wp2, bp2, out);
}